// Round 4
// baseline (12774.883 us; speedup 1.0000x reference)
//
#include <hip/hip_runtime.h>

// Problem constants
#define NB    64
#define TT    2048
#define FRAME 512
#define ENC   256
#define HID   128
#define G4    512          // 4*HID
#define ROWS  (NB*TT)      // 131072
#define DEC_OFF 67108864   // decoded elements; out_states follow

#define SB    16           // samples per LSTM block
#define HLDS  132          // padded LDS row stride (u32): 528B rows (16B-aligned), <=2-way banks

typedef __attribute__((ext_vector_type(8))) short s16x8;   // 8 bf16 (4 VGPRs)
typedef __attribute__((ext_vector_type(4))) float f32x4;   // MFMA accumulator

union UW4 { unsigned u[4]; s16x8 v; };

__device__ __forceinline__ float sigmoidf_(float x) { return 1.f / (1.f + __expf(-x)); }
__device__ __forceinline__ float tanhf_(float x)    { return 1.f - 2.f / (1.f + __expf(2.f * x)); }

// pack fp32 -> (bf16 hi | bf16 lo) in one u32. hi = truncated top16 (exact
// residual lo = x - hi by Sterbenz), lo = truncated bf16 of residual.
__device__ __forceinline__ unsigned pack_hilo(float x) {
    unsigned xb = __float_as_uint(x);
    unsigned hb = xb & 0xffff0000u;
    float lo = x - __uint_as_float(hb);
    return hb | (__float_as_uint(lo) >> 16);
}

// ---------------------------------------------------------------------------
// K0: zero the reduction accumulators
// ---------------------------------------------------------------------------
__global__ void zero_red(float* p) { p[threadIdx.x] = 0.f; }

// ---------------------------------------------------------------------------
// Tiled fp32 GEMM: C[row][col] = epi( sum_k A[row][k]*B[col][k] + bias[col] )
// Tile 128x128, K-slab 16, 256 threads, 8x8 micro-tile.
// AMODE 0: A row-major [row][K]
// AMODE 1: A = y1 layout [n][k][t], row=(n,t)   (K1 encoder)
// EPI 0: plain (+bias if non-null)
// EPI 1: plain + global sum/sumsq atomics into red[0..1]   (K1)
// EPI 2: v = sigmoid(acc+bias[c]) * aux[r][c]              (mask*enc, in-place)
// ---------------------------------------------------------------------------
template<int AMODE, int EPI>
__global__ __launch_bounds__(256, 4)
void gemm_k(const float* __restrict__ A, const float* __restrict__ Bm,
            float* __restrict__ C, const float* __restrict__ bias,
            const float* __restrict__ aux, float* __restrict__ red,
            int K, int ldc)
{
    __shared__ float As[16 * 129];
    __shared__ float Bs[16 * 129];
    const int tid = threadIdx.x;
    const int tx = tid & 15, ty = tid >> 4;
    const int rowbase = blockIdx.x * 128;
    const int colbase = blockIdx.y * 128;
    const int n = rowbase >> 11, t0 = rowbase & 2047;   // AMODE 1 only

    float acc[8][8];
#pragma unroll
    for (int i = 0; i < 8; i++)
#pragma unroll
        for (int j = 0; j < 8; j++) acc[i][j] = 0.f;

    for (int kb = 0; kb < K; kb += 16) {
#pragma unroll
        for (int it = 0; it < 8; it++) {
            const int e = it * 256 + tid;
            if (AMODE == 1) {
                const int r_i = e & 127, k_i = e >> 7;
                As[k_i * 129 + r_i] = A[((size_t)n * FRAME + kb + k_i) * TT + t0 + r_i];
            } else {
                const int k_i = e & 15, r_i = e >> 4;
                As[k_i * 129 + r_i] = A[(size_t)(rowbase + r_i) * K + kb + k_i];
            }
            const int k_i = e & 15, c_i = e >> 4;
            Bs[k_i * 129 + c_i] = Bm[(size_t)(colbase + c_i) * K + kb + k_i];
        }
        __syncthreads();
#pragma unroll
        for (int kk = 0; kk < 16; kk++) {
            float a[8], b[8];
#pragma unroll
            for (int i = 0; i < 8; i++) a[i] = As[kk * 129 + ty * 8 + i];
#pragma unroll
            for (int j = 0; j < 8; j++) b[j] = Bs[kk * 129 + tx + 16 * j];
#pragma unroll
            for (int i = 0; i < 8; i++)
#pragma unroll
                for (int j = 0; j < 8; j++) acc[i][j] = fmaf(a[i], b[j], acc[i][j]);
        }
        __syncthreads();
    }

    float s = 0.f, ss = 0.f;
#pragma unroll
    for (int i = 0; i < 8; i++) {
        const int r = rowbase + ty * 8 + i;
#pragma unroll
        for (int j = 0; j < 8; j++) {
            const int cix = colbase + tx + 16 * j;
            float v = acc[i][j];
            if (EPI == 0) { if (bias) v += bias[cix]; }
            else if (EPI == 2) {
                v = sigmoidf_(v + bias[cix]);
                v *= aux[(size_t)r * ldc + cix];
            }
            C[(size_t)r * ldc + cix] = v;
            if (EPI == 1) { s += v; ss += v * v; }
        }
    }
    if (EPI == 1) {
        __syncthreads();
        As[tid] = s; As[256 + tid] = ss;
        __syncthreads();
        for (int st = 128; st > 0; st >>= 1) {
            if (tid < st) { As[tid] += As[tid + st]; As[256 + tid] += As[256 + tid + st]; }
            __syncthreads();
        }
        if (tid == 0) { atomicAdd(&red[0], As[0]); atomicAdd(&red[1], As[256]); }
    }
}

// ---------------------------------------------------------------------------
// K2: finalize mean/var; fold LayerNorm into Wih1 -> Wf, bias1f; bias2f.
// ---------------------------------------------------------------------------
__global__ __launch_bounds__(256)
void fold_norm(const float* __restrict__ red, const float* __restrict__ Wih1,
               const float* __restrict__ gamma, const float* __restrict__ beta,
               const float* __restrict__ bih1, const float* __restrict__ bhh1,
               const float* __restrict__ bih2, const float* __restrict__ bhh2,
               float* __restrict__ Wf, float* __restrict__ b1f, float* __restrict__ b2f)
{
    const int j = blockIdx.x;      // gate row 0..511
    const int c = threadIdx.x;     // channel 0..255
    const float M = (float)ROWS * (float)ENC;   // 33554432
    const float mean = red[0] / M;
    const float var  = red[1] / M - mean * mean;
    const float rstd = rsqrtf(var + 1e-7f);
    const float scale = gamma[c] * rstd;
    const float shift = beta[c] - mean * scale;
    const float w = Wih1[j * ENC + c];
    Wf[j * ENC + c] = w * scale;
    __shared__ float rbuf[256];
    rbuf[c] = w * shift;
    __syncthreads();
    for (int s = 128; s > 0; s >>= 1) {
        if (c < s) rbuf[c] += rbuf[c + s];
        __syncthreads();
    }
    if (c == 0) {
        b1f[j] = bih1[j] + bhh1[j] + rbuf[0];
        b2f[j] = bih2[j] + bhh2[j];
    }
}

// ---------------------------------------------------------------------------
// Batched MFMA LSTM. Grid = NB/SB = 4 blocks, 512 threads (8 waves).
// Block handles SB=16 samples; per step computes D[16 x 512] =
// H[16 x 128] @ Whh^T[128 x 512] on the matrix pipe with split-bf16
// (x = hi + lo; x*w ~= hi*whi + hi*wlo + lo*whi, fp32 accumulate).
//
// Tiling (mfma_f32_16x16x32_bf16): M=16 (1 tile, samples), K=128 (4 tiles,
// hidden units), N=512 gate cols (32 tiles). Wave w owns N-tiles
// {w, w+8, w+16, w+24} => cols gb*128 + (16w + lane&15), gb = gate i/f/g/o.
// D lane layout (HW-verified): row(sample) = 4*(lane>>4)+reg, col = lane&15.
// => each lane holds ALL FOUR gates of unit j = 16w+(lane&15) for samples
// s = 4*(lane>>4)+{0..3}: activations + c,h update are lane-local.
//
// A/B fragments use the SAME lane->k permutation (k = 8*(lane>>4)+e within
// each 32-tile), so the dot product is correct independent of the HW's
// internal k-order (permutation-invariance of sum over k).
//
// Whh hi/lo B-fragments: built once in prologue, 128 VGPRs, static.
// H state: (hi|lo)-packed u32 in LDS [SB][HLDS] (16B-aligned rows),
// double-buffered, ONE barrier/step. acc initialized from xg (free bias add
// via MFMA C-in); xg reads in the native [n][t][4H] layout are 4x64B
// coalesced segments per load instruction.
// __launch_bounds__(512,2): 8-wave block resident => 256-VGPR budget.
// ---------------------------------------------------------------------------
__global__ __launch_bounds__(512, 2)
void lstm_seq(const float* __restrict__ xg, const float* __restrict__ Whh,
              const float* __restrict__ states_in, int h_idx, int c_idx,
              float* __restrict__ xout, float* __restrict__ out_states)
{
    const int tid  = threadIdx.x;
    const int lane = tid & 63;
    const int wv   = tid >> 6;          // wave 0..7
    const int kg   = lane >> 4;         // 16-lane group 0..3
    const int cx   = lane & 15;
    const int jm   = wv * 16 + cx;      // this lane's hidden unit (as output col)
    const int s0   = blockIdx.x * SB;   // first sample of this block

    // 16B alignment REQUIRED: read via uint4 (ds_read_b128)
    __shared__ __align__(16) unsigned Hbuf0[SB * HLDS];
    __shared__ __align__(16) unsigned Hbuf1[SB * HLDS];

    // ---- prologue: build Whh hi/lo B-fragments (static, 128 VGPRs) ----
    s16x8 bhi[4][4], blo[4][4];         // [gate][ktile]
#pragma unroll
    for (int gb = 0; gb < 4; gb++) {
#pragma unroll
        for (int kt = 0; kt < 4; kt++) {
            const float* wp = Whh + (size_t)(gb * HID + jm) * HID + kt * 32 + kg * 8;
            float f[8];
            *(float4*)(f)     = ((const float4*)wp)[0];
            *(float4*)(f + 4) = ((const float4*)wp)[1];
            UW4 uh, ul;
#pragma unroll
            for (int p = 0; p < 4; p++) {
                unsigned b0 = __float_as_uint(f[2 * p]);
                unsigned b1 = __float_as_uint(f[2 * p + 1]);
                unsigned h0 = b0 & 0xffff0000u, h1 = b1 & 0xffff0000u;
                float l0 = f[2 * p]     - __uint_as_float(h0);
                float l1 = f[2 * p + 1] - __uint_as_float(h1);
                uh.u[p] = (h0 >> 16) | h1;
                ul.u[p] = (__float_as_uint(l0) >> 16) | (__float_as_uint(l1) & 0xffff0000u);
            }
            bhi[gb][kt] = uh.v;
            blo[gb][kt] = ul.v;
        }
    }

    // ---- stage h0 into Hbuf0 (packed), c0 into registers ----
    for (int idx = tid; idx < SB * HID; idx += 512) {
        const int s = idx >> 7, j = idx & 127;
        Hbuf0[s * HLDS + j] = pack_hilo(states_in[h_idx * (NB * HID) + (s0 + s) * HID + j]);
    }
    float cst[4], hval[4];
#pragma unroll
    for (int r = 0; r < 4; r++) {
        cst[r] = states_in[c_idx * (NB * HID) + (s0 + 4 * kg + r) * HID + jm];
        hval[r] = 0.f;
    }
    __syncthreads();

    // ---- xg pointers (4: one per sample-slot reg), gate via imm offset ----
    const float* xgp[4];
    float* xop[4];
#pragma unroll
    for (int r = 0; r < 4; r++) {
        xgp[r] = xg   + (size_t)(s0 + 4 * kg + r) * TT * G4  + jm;
        xop[r] = xout + (size_t)(s0 + 4 * kg + r) * TT * HID + jm;
    }
    float xcur[4][4];                    // [gate][reg]
#pragma unroll
    for (int r = 0; r < 4; r++) {
#pragma unroll
        for (int gb = 0; gb < 4; gb++) xcur[gb][r] = xgp[r][gb * 128];
        xgp[r] += G4;                    // now points at t=1
    }

    // ---- one LSTM step ----
    auto lstep = [&](const unsigned* __restrict__ Hc, unsigned* __restrict__ Hn,
                     int t) {
        // prefetch xg for t+1. At t=TT-1 this reads one step past the xg
        // region -- still inside d_ws (start of xbuf), never used.
        float xnext[4][4];
#pragma unroll
        for (int r = 0; r < 4; r++) {
#pragma unroll
            for (int gb = 0; gb < 4; gb++) xnext[gb][r] = xgp[r][gb * 128];
            xgp[r] += G4;
        }
        // acc init = xg (free bias add via MFMA C-in)
        f32x4 acc[4];
#pragma unroll
        for (int gb = 0; gb < 4; gb++)
            acc[gb] = (f32x4){xcur[gb][0], xcur[gb][1], xcur[gb][2], xcur[gb][3]};
        // K loop: A-frag from LDS (sample = lane&15, units = kt*32 + 8*kg ..)
#pragma unroll
        for (int kt = 0; kt < 4; kt++) {
            const uint4* hp = (const uint4*)(Hc + cx * HLDS + kt * 32 + kg * 8);
            uint4 u0 = hp[0], u1 = hp[1];
            unsigned uw[8] = {u0.x, u0.y, u0.z, u0.w, u1.x, u1.y, u1.z, u1.w};
            UW4 uah, ual;
#pragma unroll
            for (int p = 0; p < 4; p++) {
                uah.u[p] = (uw[2 * p] >> 16)      | (uw[2 * p + 1] & 0xffff0000u);
                ual.u[p] = (uw[2 * p] & 0xffffu)  | (uw[2 * p + 1] << 16);
            }
            const s16x8 Ahi = uah.v, Alo = ual.v;
#pragma unroll
            for (int gb = 0; gb < 4; gb++)
                acc[gb] = __builtin_amdgcn_mfma_f32_16x16x32_bf16(Ahi, bhi[gb][kt], acc[gb], 0, 0, 0);
#pragma unroll
            for (int gb = 0; gb < 4; gb++)
                acc[gb] = __builtin_amdgcn_mfma_f32_16x16x32_bf16(Ahi, blo[gb][kt], acc[gb], 0, 0, 0);
#pragma unroll
            for (int gb = 0; gb < 4; gb++)
                acc[gb] = __builtin_amdgcn_mfma_f32_16x16x32_bf16(Alo, bhi[gb][kt], acc[gb], 0, 0, 0);
        }
        // activations + state update (all lane-local)
#pragma unroll
        for (int r = 0; r < 4; r++) {
            const float ig = sigmoidf_(acc[0][r]);
            const float fg = sigmoidf_(acc[1][r]);
            const float gg = tanhf_(acc[2][r]);
            const float og = sigmoidf_(acc[3][r]);
            cst[r] = fmaf(fg, cst[r], ig * gg);
            const float hv = og * tanhf_(cst[r]);
            hval[r] = hv;
            Hn[(4 * kg + r) * HLDS + jm] = pack_hilo(hv);
            xop[r][0] = hv;
            xop[r] += HID;
        }
#pragma unroll
        for (int gb = 0; gb < 4; gb++)
#pragma unroll
            for (int r = 0; r < 4; r++) xcur[gb][r] = xnext[gb][r];
        __syncthreads();
    };

    for (int t = 0; t < TT; t += 2) {
        lstep(Hbuf0, Hbuf1, t);
        lstep(Hbuf1, Hbuf0, t + 1);
    }

#pragma unroll
    for (int r = 0; r < 4; r++) {
        out_states[h_idx * (NB * HID) + (s0 + 4 * kg + r) * HID + jm] = hval[r];
        out_states[c_idx * (NB * HID) + (s0 + 4 * kg + r) * HID + jm] = cst[r];
    }
}

// ---------------------------------------------------------------------------
// K6: transpose [N][T][512] -> [N][512][T] (final decoded layout)
// ---------------------------------------------------------------------------
__global__ __launch_bounds__(256)
void transpose_nt(const float* __restrict__ src, float* __restrict__ dst)
{
    __shared__ float tile[32][33];
    const int n  = blockIdx.z;
    const int t0 = blockIdx.x * 32;
    const int o0 = blockIdx.y * 32;
    const int lx = threadIdx.x, ly = threadIdx.y;   // 32 x 8
    for (int r = ly; r < 32; r += 8)
        tile[r][lx] = src[((size_t)n * TT + t0 + r) * FRAME + o0 + lx];
    __syncthreads();
    for (int r = ly; r < 32; r += 8)
        dst[((size_t)n * FRAME + o0 + r) * TT + t0 + lx] = tile[lx][r];
}

// ---------------------------------------------------------------------------
extern "C" void kernel_launch(void* const* d_in, const int* in_sizes, int n_in,
                              void* d_out, int out_size, void* d_ws, size_t ws_size,
                              hipStream_t stream)
{
    const float* y1     = (const float*)d_in[0];
    const float* states = (const float*)d_in[1];
    const float* W_enc  = (const float*)d_in[2];
    const float* gamma  = (const float*)d_in[3];
    const float* beta   = (const float*)d_in[4];
    const float* Wih1   = (const float*)d_in[5];
    const float* Whh1   = (const float*)d_in[6];
    const float* bih1   = (const float*)d_in[7];
    const float* bhh1   = (const float*)d_in[8];
    const float* Wih2   = (const float*)d_in[9];
    const float* Whh2   = (const float*)d_in[10];
    const float* bih2   = (const float*)d_in[11];
    const float* bhh2   = (const float*)d_in[12];
    const float* Wd     = (const float*)d_in[13];
    const float* bd     = (const float*)d_in[14];
    const float* W_dec  = (const float*)d_in[15];

    float* out = (float*)d_out;
    float* out_states = out + DEC_OFF;

    // workspace layout (floats)
    float* ws    = (float*)d_ws;
    float* encf  = ws;                                  // [N][T][256]  33,554,432
    float* xg    = encf + (size_t)ROWS * ENC;           // [N][T][512]  67,108,864
    float* xbuf  = xg + (size_t)ROWS * G4;              // [N][T][128]  16,777,216
    float* Wf    = xbuf + (size_t)ROWS * HID;           // [512][256]
    float* b1f   = Wf + G4 * ENC;                       // [512]
    float* b2f   = b1f + G4;                            // [512]
    float* red   = b2f + G4;                            // [2]
    const size_t needed = (size_t)(red + 2 - ws) * sizeof(float);
    if (ws_size < needed) return;   // insufficient scratch: fail loudly

    const dim3 blk(256);

    // K0: zero reduction scalars
    zero_red<<<1, 2, 0, stream>>>(red);

    // K1: encf = y1^T @ W_enc^T  (per n), + global sum/sumsq
    gemm_k<1, 1><<<dim3(ROWS / 128, ENC / 128), blk, 0, stream>>>(
        y1, W_enc, encf, nullptr, nullptr, red, FRAME, ENC);

    // K2: fold LN into Wih1
    fold_norm<<<G4, 256, 0, stream>>>(red, Wih1, gamma, beta, bih1, bhh1,
                                      bih2, bhh2, Wf, b1f, b2f);

    // K3: xg1 = encf @ Wf^T + b1f
    gemm_k<0, 0><<<dim3(ROWS / 128, G4 / 128), blk, 0, stream>>>(
        encf, Wf, xg, b1f, nullptr, nullptr, ENC, G4);

    // K4a: LSTM1 (batched MFMA) -> xbuf (=x1), states h1,c1
    lstm_seq<<<NB / SB, 512, 0, stream>>>(xg, Whh1, states, 0, 1, xbuf, out_states);

    // K4b: xg2 = x1 @ Wih2^T + b2f  (overwrites xg)
    gemm_k<0, 0><<<dim3(ROWS / 128, G4 / 128), blk, 0, stream>>>(
        xbuf, Wih2, xg, b2f, nullptr, nullptr, HID, G4);

    // K4c: LSTM2 (batched MFMA) -> xbuf (=x2), states h2,c2
    lstm_seq<<<NB / SB, 512, 0, stream>>>(xg, Whh2, states, 2, 3, xbuf, out_states);

    // K5a: est = sigmoid(x2 @ Wd^T + bd) * encf   (in-place into encf)
    gemm_k<0, 2><<<dim3(ROWS / 128, ENC / 128), blk, 0, stream>>>(
        xbuf, Wd, encf, bd, encf, nullptr, HID, ENC);

    // K5b: Ctmp = est @ W_dec^T   (row-major [N][T][512] into xg)
    gemm_k<0, 0><<<dim3(ROWS / 128, G4 / 128), blk, 0, stream>>>(
        encf, W_dec, xg, nullptr, nullptr, nullptr, ENC, G4);

    // K6: transpose -> decoded [N][512][T]
    transpose_nt<<<dim3(TT / 32, FRAME / 32, NB), dim3(32, 8), 0, stream>>>(xg, out);
}